// Round 5
// baseline (16909.158 us; speedup 1.0000x reference)
//
#include <hip/hip_runtime.h>
#include <hip/hip_fp16.h>
#include <math.h>

// Scalar fp32 reference-grade kernel: one block per ray, 256 threads (4 waves).
// act [128][256] fp32 in LDS, updated layer-by-layer IN PLACE:
//   out[m][n] = sum_k act[m][k] * W[k][n]  — row m depends only on row m, so
//   per-16-row chunks with (compute -> barrier -> write -> barrier) are race-free.
// Thread mapping: group g = tid>>7 owns rows [64g, 64g+64); col c0 = tid&127,
// and c1 = c0+128 when N=256. Weight columns cached in VGPRs per 64-k tile.

__device__ void dense_layer(float* act, const __half* pxh,
                            const float* __restrict__ W,   // act-part rows [256][ldw] (may be null if nkt==0)
                            const float* __restrict__ Wx,  // px-part rows [Kx][ldw] (may be null)
                            int ldw, const float* __restrict__ bias,
                            int nkt, int Kx, int N, float pdadd, bool relu, int tid) {
  const int g  = tid >> 7;
  const int c0 = tid & 127;
  const int c1 = c0 + 128;
  const bool two = (N > 128);
  for (int ch = 0; ch < 4; ++ch) {
    const int r0 = g * 64 + ch * 16;
    float acc0[16], acc1[16];
#pragma unroll
    for (int mm = 0; mm < 16; ++mm) { acc0[mm] = pdadd; acc1[mm] = 0.f; }
    for (int kt = 0; kt < nkt; ++kt) {
      float w0r[64], w1r[64];
#pragma unroll
      for (int j = 0; j < 64; ++j) w0r[j] = W[(kt * 64 + j) * ldw + c0];
      if (two) {
#pragma unroll
        for (int j = 0; j < 64; ++j) w1r[j] = W[(kt * 64 + j) * ldw + c1];
      }
#pragma unroll
      for (int mm = 0; mm < 16; ++mm) {
        const float* ar = act + (r0 + mm) * 256 + kt * 64;
        float s0 = 0.f, s1 = 0.f;
#pragma unroll
        for (int j = 0; j < 64; ++j) {
          float a = ar[j];
          s0 += a * w0r[j];
          if (two) s1 += a * w1r[j];
        }
        acc0[mm] += s0; if (two) acc1[mm] += s1;
      }
    }
    if (Kx > 0) {   // positional-encoding addon (rows of Wx), px in fp16 LDS
      float w0x[60], w1x[60];
#pragma unroll
      for (int j = 0; j < 60; ++j) w0x[j] = Wx[j * ldw + c0];
      if (two) {
#pragma unroll
        for (int j = 0; j < 60; ++j) w1x[j] = Wx[j * ldw + c1];
      }
#pragma unroll
      for (int mm = 0; mm < 16; ++mm) {
        const __half* pr = pxh + (r0 + mm) * 60;
        float s0 = 0.f, s1 = 0.f;
#pragma unroll
        for (int j = 0; j < 60; ++j) {
          float a = __half2float(pr[j]);
          s0 += a * w0x[j];
          if (two) s1 += a * w1x[j];
        }
        acc0[mm] += s0; if (two) acc1[mm] += s1;
      }
    }
    __syncthreads();   // all reads of this row-chunk complete
    {
      float bv0 = bias[c0];
      float bv1 = two ? bias[c1] : 0.f;
#pragma unroll
      for (int mm = 0; mm < 16; ++mm) {
        float v0 = acc0[mm] + bv0;
        if (relu) v0 = fmaxf(v0, 0.f);
        act[(r0 + mm) * 256 + c0] = v0;
        if (two) {
          float v1 = acc1[mm] + bv1;
          if (relu) v1 = fmaxf(v1, 0.f);
          act[(r0 + mm) * 256 + c1] = v1;
        }
      }
    }
    __syncthreads();   // writes visible before next chunk / next layer
  }
}

__global__ __launch_bounds__(256) void nerf_scalar(
    const float* __restrict__ ro, const float* __restrict__ rd, const float* __restrict__ tin,
    const float* __restrict__ W0, const float* __restrict__ b0,
    const float* __restrict__ Wh, const float* __restrict__ bh,
    const float* __restrict__ W5, const float* __restrict__ b5,
    const float* __restrict__ W6, const float* __restrict__ b6,
    const float* __restrict__ W7, const float* __restrict__ b7,
    const float* __restrict__ Wsig, const float* __restrict__ bs,
    const float* __restrict__ Wf, const float* __restrict__ bfb,
    const float* __restrict__ Wm, const float* __restrict__ bm,
    const float* __restrict__ Wr, const float* __restrict__ br,
    float* __restrict__ out) {
  __shared__ float  act[128 * 256];   // 131072 B
  __shared__ __half pxh[128 * 60];    //  15360 B
  __shared__ float  pdBuf[24];
  __shared__ float  tBuf[128];
  __shared__ float  sigBuf[128];
  __shared__ float  rgbBuf[128 * 3];
  __shared__ float  red[256];
  __shared__ float  red3[3 * 256];

  const int b   = blockIdx.x;
  const int tid = threadIdx.x;

  // ---- positional encodings (fp32 math; px stored fp16) ----
  if (tid < 128) {
    const int m = tid;
    float tv = tin[b * 128 + m];
    tBuf[m] = tv;
    float xs[3];
#pragma unroll
    for (int c = 0; c < 3; ++c) xs[c] = ro[b * 3 + c] + tv * rd[b * 3 + c];
#pragma unroll
    for (int i = 0; i < 10; ++i)
#pragma unroll
      for (int c = 0; c < 3; ++c) {
        float a = ldexpf(xs[c], i);                 // sin(2^i*pi*x) = sinpi(2^i*x)
        pxh[m * 60 + i * 6 + c]     = __float2half(sinpif(a));
        pxh[m * 60 + i * 6 + 3 + c] = __float2half(cospif(a));
      }
  } else if (tid < 152) {
    int j = tid - 128;                               // 24 pd values, per ray
    int i = j / 6, r = j % 6;
    float a = ldexpf(rd[b * 3 + (r % 3)], i);
    pdBuf[j] = (r < 3) ? sinpif(a) : cospif(a);
  }
  __syncthreads();

  // layer 0: relu(px @ W0 + b0)                       W0 [60][256]
  dense_layer(act, pxh, nullptr, W0, 256, b0, 0, 60, 256, 0.f, true, tid);
  // layers 1..4                                       Wh [4][256][256]
  for (int i = 0; i < 4; ++i)
    dense_layer(act, pxh, Wh + i * 65536, nullptr, 256, bh + i * 256, 4, 0, 256, 0.f, true, tid);
  // layer 5: relu([h, px] @ W5 + b5)                  W5 [316][256]
  dense_layer(act, pxh, W5, W5 + 256 * 256, 256, b5, 4, 60, 256, 0.f, true, tid);
  // layers 6, 7
  dense_layer(act, pxh, W6, nullptr, 256, b6, 4, 0, 256, 0.f, true, tid);
  dense_layer(act, pxh, W7, nullptr, 256, b7, 4, 0, 256, 0.f, true, tid);

  // sigma = relu(h @ Ws + bs): 2 threads per sample
  {
    const int m = tid >> 1, q = tid & 1;
    float s = 0.f;
    for (int k = q * 128; k < q * 128 + 128; ++k) s += act[m * 256 + k] * Wsig[k];
    red[tid] = s;
    __syncthreads();
    if (tid < 128) sigBuf[tid] = fmaxf(red[2 * tid] + red[2 * tid + 1] + bs[0], 0.f);
    __syncthreads();
  }

  // feat = h @ Wf + bf (no relu)
  dense_layer(act, pxh, Wf, nullptr, 256, bfb, 4, 0, 256, 0.f, false, tid);

  // h2 = relu([feat, pd] @ Wm + bm)                   Wm [280][128], N = 128
  {
    float pda = 0.f;                                  // pd part is per-ray: hoist
    const int c0 = tid & 127;
#pragma unroll
    for (int j = 0; j < 24; ++j) pda += pdBuf[j] * Wm[(256 + j) * 128 + c0];
    dense_layer(act, pxh, Wm, nullptr, 128, bm, 4, 0, 128, pda, true, tid);
  }

  // rgb = sigmoid(h2 @ Wr + br): 2 threads per sample over K=128
  {
    const int m = tid >> 1, q = tid & 1;
    float r0s = 0.f, r1s = 0.f, r2s = 0.f;
    for (int k = q * 64; k < q * 64 + 64; ++k) {
      float hv = act[m * 256 + k];
      r0s += hv * Wr[k * 3 + 0];
      r1s += hv * Wr[k * 3 + 1];
      r2s += hv * Wr[k * 3 + 2];
    }
    red3[tid] = r0s; red3[256 + tid] = r1s; red3[512 + tid] = r2s;
    __syncthreads();
    if (tid < 128) {
#pragma unroll
      for (int c = 0; c < 3; ++c) {
        float sm = red3[c * 256 + 2 * tid] + red3[c * 256 + 2 * tid + 1] + br[c];
        rgbBuf[tid * 3 + c] = 1.f / (1.f + expf(-sm));
      }
    }
    __syncthreads();
  }

  // volume rendering: serial exclusive-transmittance scan
  if (tid == 0) {
    float T = 1.f, c0 = 0.f, c1 = 0.f, c2 = 0.f, wsum = 0.f;
    for (int m = 0; m < 128; ++m) {
      float delta = (m < 127) ? (tBuf[m + 1] - tBuf[m]) : 1e8f;
      float e = expf(-sigBuf[m] * delta);
      float w = T * (1.f - e);
      c0 += w * rgbBuf[m * 3 + 0];
      c1 += w * rgbBuf[m * 3 + 1];
      c2 += w * rgbBuf[m * 3 + 2];
      wsum += w;
      T *= e;
    }
    float bg = 1.f - wsum;   // C_BG = (1,1,1)
    out[b * 3 + 0] = c0 + bg;
    out[b * 3 + 1] = c1 + bg;
    out[b * 3 + 2] = c2 + bg;
  }
}

extern "C" void kernel_launch(void* const* d_in, const int* in_sizes, int n_in,
                              void* d_out, int out_size, void* d_ws, size_t ws_size,
                              hipStream_t stream) {
  const float* ro  = (const float*)d_in[0];
  const float* rd  = (const float*)d_in[1];
  const float* t   = (const float*)d_in[2];
  const float* W0  = (const float*)d_in[3];
  const float* b0  = (const float*)d_in[4];
  const float* Wh  = (const float*)d_in[5];
  const float* bh  = (const float*)d_in[6];
  const float* W5  = (const float*)d_in[7];
  const float* b5  = (const float*)d_in[8];
  const float* W6  = (const float*)d_in[9];
  const float* b6  = (const float*)d_in[10];
  const float* W7  = (const float*)d_in[11];
  const float* b7  = (const float*)d_in[12];
  const float* Wsg = (const float*)d_in[13];
  const float* bs  = (const float*)d_in[14];
  const float* Wf  = (const float*)d_in[15];
  const float* bfb = (const float*)d_in[16];
  const float* Wm  = (const float*)d_in[17];
  const float* bm  = (const float*)d_in[18];
  const float* Wr  = (const float*)d_in[19];
  const float* br  = (const float*)d_in[20];
  float* out = (float*)d_out;

  nerf_scalar<<<2048, 256, 0, stream>>>(ro, rd, t, W0, b0, Wh, bh, W5, b5, W6, b6,
                                        W7, b7, Wsg, bs, Wf, bfb, Wm, bm, Wr, br, out);
}

// Round 9
// 3776.619 us; speedup vs baseline: 4.4773x; 4.4773x over previous
//
#include <hip/hip_runtime.h>
#include <hip/hip_fp16.h>
#include <math.h>

typedef __bf16 bf16x8 __attribute__((ext_vector_type(8)));
typedef float  f32x4  __attribute__((ext_vector_type(4)));

#define AST 260              // act row stride (fp32 elems): 260%32==4 -> conflict-light
#define TOT 589824           // staged weight elems (hi); lo at +TOT

// staged ws layout (bf16, [n][k] transposed, zero-padded K tails)
#define OFF_W0T   0          // [256][64]
#define OFF_WHT   16384      // 4 x [256][256]
#define OFF_W5AT  278528     // [256][256]
#define OFF_W5BT  344064     // [256][64]
#define OFF_W6T   360448     // [256][256]
#define OFF_W7T   425984     // [256][256]
#define OFF_WFT   491520     // [256][256]
#define OFF_WMAT  557056     // [128][256]

__global__ void prep_weights(const float* __restrict__ W0, const float* __restrict__ Wh,
                             const float* __restrict__ W5, const float* __restrict__ W6,
                             const float* __restrict__ W7, const float* __restrict__ Wf,
                             const float* __restrict__ Wm, __bf16* __restrict__ ws) {
  int idx = blockIdx.x * blockDim.x + threadIdx.x;
  if (idx >= TOT) return;
  float v = 0.f;
  if (idx < OFF_WHT)        { int j = idx;            int n=j>>6, k=j&63;   v = (k<60)? W0[k*256+n] : 0.f; }
  else if (idx < OFF_W5AT)  { int j = idx - OFF_WHT;  int i=j>>16, r=j&65535, n=r>>8, k=r&255; v = Wh[i*65536+k*256+n]; }
  else if (idx < OFF_W5BT)  { int j = idx - OFF_W5AT; int n=j>>8, k=j&255;  v = W5[k*256+n]; }
  else if (idx < OFF_W6T)   { int j = idx - OFF_W5BT; int n=j>>6, k=j&63;   v = (k<60)? W5[(256+k)*256+n] : 0.f; }
  else if (idx < OFF_W7T)   { int j = idx - OFF_W6T;  int n=j>>8, k=j&255;  v = W6[k*256+n]; }
  else if (idx < OFF_WFT)   { int j = idx - OFF_W7T;  int n=j>>8, k=j&255;  v = W7[k*256+n]; }
  else if (idx < OFF_WMAT)  { int j = idx - OFF_WFT;  int n=j>>8, k=j&255;  v = Wf[k*256+n]; }
  else                      { int j = idx - OFF_WMAT; int n=j>>8, k=j&255;  v = Wm[k*128+n]; }
  __bf16 hi = (__bf16)v;
  ws[idx] = hi;
  ws[TOT + idx] = (__bf16)(v - (float)hi);
}

// ---------------- scalar fp32 layer (round-5, PASSED; stride AST) ----------------
__device__ void dense_layer(float* act, const __half* pxh,
                            const float* __restrict__ W, const float* __restrict__ Wx,
                            int ldw, const float* __restrict__ bias,
                            int nkt, bool usePx, int N, float pdadd, bool relu, int tid) {
  const int g  = tid >> 7;
  const int c0 = tid & 127;
  const int c1 = c0 + 128;
  const bool two = (N > 128);
  for (int ch = 0; ch < 4; ++ch) {
    const int r0 = g * 64 + ch * 16;
    float acc0[16], acc1[16];
#pragma unroll
    for (int mm = 0; mm < 16; ++mm) { acc0[mm] = pdadd; acc1[mm] = 0.f; }
    for (int kt = 0; kt < nkt; ++kt) {
      float w0r[64], w1r[64];
#pragma unroll
      for (int j = 0; j < 64; ++j) w0r[j] = W[(kt*64 + j)*ldw + c0];
      if (two) {
#pragma unroll
        for (int j = 0; j < 64; ++j) w1r[j] = W[(kt*64 + j)*ldw + c1];
      }
#pragma unroll
      for (int mm = 0; mm < 16; ++mm) {
        const float* ar = act + (r0 + mm)*AST + kt*64;
        float s0 = 0.f, s1 = 0.f;
#pragma unroll
        for (int j = 0; j < 64; ++j) {
          float a = ar[j];
          s0 += a * w0r[j];
          if (two) s1 += a * w1r[j];
        }
        acc0[mm] += s0; if (two) acc1[mm] += s1;
      }
    }
    if (usePx) {
      float w0x[60], w1x[60];
#pragma unroll
      for (int j = 0; j < 60; ++j) w0x[j] = Wx[j*ldw + c0];
      if (two) {
#pragma unroll
        for (int j = 0; j < 60; ++j) w1x[j] = Wx[j*ldw + c1];
      }
#pragma unroll
      for (int mm = 0; mm < 16; ++mm) {
        const __half* pr = pxh + (r0 + mm)*64;
        float s0 = 0.f, s1 = 0.f;
#pragma unroll
        for (int j = 0; j < 60; ++j) {
          float a = __half2float(pr[j]);
          s0 += a * w0x[j];
          if (two) s1 += a * w1x[j];
        }
        acc0[mm] += s0; if (two) acc1[mm] += s1;
      }
    }
    __syncthreads();
    {
      float bv0 = bias[c0];
      float bv1 = two ? bias[c1] : 0.f;
#pragma unroll
      for (int mm = 0; mm < 16; ++mm) {
        float v0 = acc0[mm] + bv0;
        if (relu) v0 = fmaxf(v0, 0.f);
        act[(r0 + mm)*AST + c0] = v0;
        if (two) {
          float v1 = acc1[mm] + bv1;
          if (relu) v1 = fmaxf(v1, 0.f);
          act[(r0 + mm)*AST + c1] = v1;
        }
      }
    }
    __syncthreads();
  }
}

__device__ __forceinline__ void split8f(const float* s, bf16x8& hi, bf16x8& lo) {
#pragma unroll
  for (int j = 0; j < 8; ++j) {
    float v = s[j];
    __bf16 h = (__bf16)v;
    hi[j] = h;
    lo[j] = (__bf16)(v - (float)h);
  }
}

// fp32 reference for one output element (uses ORIGINAL fp32 weights)
__device__ float chk_ref(const float* act, const __half* pxh,
                         const float* __restrict__ Wref, const float* __restrict__ WxRef,
                         int ldwRef, int nkc, int row, int col) {
  float ref = 0.f;
  for (int k = 0; k < nkc*32; ++k) ref += act[row*AST + k] * Wref[k*ldwRef + col];
  if (WxRef)
    for (int k = 0; k < 60; ++k) ref += __half2float(pxh[row*64 + k]) * WxRef[k*ldwRef + col];
  return ref;
}

// ------- split-bf16 3-pass MFMA layer, self-checked; false -> act untouched -------
template<int NT>
__device__ bool mfma_layer(float* act, const __half* pxh,
    const __bf16* __restrict__ wHi, const __bf16* __restrict__ wLo, int kStr,   // staged [N][K]
    const __bf16* __restrict__ xHi, const __bf16* __restrict__ xLo,             // px staged [N][64] or null
    const float* __restrict__ Wref, const float* __restrict__ WxRef, int ldwRef,
    const float* __restrict__ bias, int nkc,
    const float* pdW, bool relu, int tid, int* bad) {
  const int wave = tid >> 6, lane = tid & 63;
  const int lm = lane & 15, kq = lane >> 4;
  const int mBase = (wave >> 1) * 64;
  const int nBase = (wave & 1) * (NT * 16);
  f32x4 acc[4][NT];
#pragma unroll
  for (int mt = 0; mt < 4; ++mt)
#pragma unroll
    for (int nt = 0; nt < NT; ++nt)
#pragma unroll
      for (int e = 0; e < 4; ++e) acc[mt][nt][e] = 0.f;

  for (int kc = 0; kc < nkc; ++kc) {           // act part
    const int kb = kc*32 + kq*8;
    bf16x8 ahi[4], alo[4], bhi[NT], blo[NT];
#pragma unroll
    for (int mt = 0; mt < 4; ++mt)
      split8f(act + (mBase + mt*16 + lm)*AST + kb, ahi[mt], alo[mt]);
#pragma unroll
    for (int nt = 0; nt < NT; ++nt) {
      const int ro = (nBase + nt*16 + lm)*kStr + kb;
      bhi[nt] = *(const bf16x8*)(wHi + ro);
      blo[nt] = *(const bf16x8*)(wLo + ro);
    }
#pragma unroll
    for (int mt = 0; mt < 4; ++mt)
#pragma unroll
      for (int nt = 0; nt < NT; ++nt) {
        acc[mt][nt] = __builtin_amdgcn_mfma_f32_16x16x32_bf16(ahi[mt], bhi[nt], acc[mt][nt], 0, 0, 0);
        acc[mt][nt] = __builtin_amdgcn_mfma_f32_16x16x32_bf16(ahi[mt], blo[nt], acc[mt][nt], 0, 0, 0);
        acc[mt][nt] = __builtin_amdgcn_mfma_f32_16x16x32_bf16(alo[mt], bhi[nt], acc[mt][nt], 0, 0, 0);
      }
  }
  if (xHi) {                                   // px part, K=64 (zero-padded tail)
#pragma unroll
    for (int kc = 0; kc < 2; ++kc) {
      const int kb = kc*32 + kq*8;
      bf16x8 ahi[4], alo[4], bhi[NT], blo[NT];
#pragma unroll
      for (int mt = 0; mt < 4; ++mt) {
        const __half* pr = pxh + (mBase + mt*16 + lm)*64 + kb;
#pragma unroll
        for (int j = 0; j < 8; ++j) {
          float v = __half2float(pr[j]);
          __bf16 h = (__bf16)v;
          ahi[mt][j] = h;
          alo[mt][j] = (__bf16)(v - (float)h);
        }
      }
#pragma unroll
      for (int nt = 0; nt < NT; ++nt) {
        const int ro = (nBase + nt*16 + lm)*64 + kb;
        bhi[nt] = *(const bf16x8*)(xHi + ro);
        blo[nt] = *(const bf16x8*)(xLo + ro);
      }
#pragma unroll
      for (int mt = 0; mt < 4; ++mt)
#pragma unroll
        for (int nt = 0; nt < NT; ++nt) {
          acc[mt][nt] = __builtin_amdgcn_mfma_f32_16x16x32_bf16(ahi[mt], bhi[nt], acc[mt][nt], 0, 0, 0);
          acc[mt][nt] = __builtin_amdgcn_mfma_f32_16x16x32_bf16(ahi[mt], blo[nt], acc[mt][nt], 0, 0, 0);
          acc[mt][nt] = __builtin_amdgcn_mfma_f32_16x16x32_bf16(alo[mt], bhi[nt], acc[mt][nt], 0, 0, 0);
        }
    }
  }

  // 3 fp32-reference samples/thread (compile-time tile idx; r=0,1,3 pins row perm)
  bool mism = false;
  {
    float got, ref; int row, col;
    row = mBase + 0*16 + kq*4 + 0;  col = nBase + 0*16 + lm;
    got = acc[0][0][0];
    ref = chk_ref(act, pxh, Wref, WxRef, ldwRef, nkc, row, col);
    if (fabsf(got - ref) > 0.05f + 0.02f*fabsf(ref)) mism = true;

    row = mBase + 1*16 + kq*4 + 1;  col = nBase + (NT > 1 ? 1 : 0)*16 + lm;
    got = acc[1][(NT > 1 ? 1 : 0)][1];
    ref = chk_ref(act, pxh, Wref, WxRef, ldwRef, nkc, row, col);
    if (fabsf(got - ref) > 0.05f + 0.02f*fabsf(ref)) mism = true;

    row = mBase + 3*16 + kq*4 + 3;  col = nBase + (NT - 1)*16 + lm;
    got = acc[3][NT - 1][3];
    ref = chk_ref(act, pxh, Wref, WxRef, ldwRef, nkc, row, col);
    if (fabsf(got - ref) > 0.05f + 0.02f*fabsf(ref)) mism = true;
  }
  __syncthreads();                 // all reads of act done
  if (tid == 0) *bad = 0;
  __syncthreads();
  if (mism) *bad = 1;
  __syncthreads();
  if (*bad) return false;          // act untouched -> caller runs dense_layer

  // epilogue: documented C/D mapping row=kq*4+r, col=lm
#pragma unroll
  for (int mt = 0; mt < 4; ++mt)
#pragma unroll
    for (int nt = 0; nt < NT; ++nt) {
      const int col = nBase + nt*16 + lm;
      float bv = bias[col] + (pdW ? pdW[col] : 0.f);
#pragma unroll
      for (int r = 0; r < 4; ++r) {
        const int row = mBase + mt*16 + kq*4 + r;
        float v = acc[mt][nt][r] + bv;
        if (relu) v = fmaxf(v, 0.f);
        act[row*AST + col] = v;
      }
    }
  __syncthreads();
  return true;
}

__global__ __launch_bounds__(256, 1) void nerf_main(
    const float* __restrict__ ro, const float* __restrict__ rd, const float* __restrict__ tin,
    const float* __restrict__ W0, const float* __restrict__ b0,
    const float* __restrict__ Wh, const float* __restrict__ bh,
    const float* __restrict__ W5, const float* __restrict__ b5,
    const float* __restrict__ W6, const float* __restrict__ b6,
    const float* __restrict__ W7, const float* __restrict__ b7,
    const float* __restrict__ Wsig, const float* __restrict__ bs,
    const float* __restrict__ Wf, const float* __restrict__ bfb,
    const float* __restrict__ Wm, const float* __restrict__ bm,
    const float* __restrict__ Wr, const float* __restrict__ br,
    const __bf16* __restrict__ wsHi, const __bf16* __restrict__ wsLo,
    int useMfma, float* __restrict__ out) {
  __shared__ float  act[128 * AST];    // 133120 B
  __shared__ __half pxh[128 * 64];     //  16384 B (cols 60..63 zero)
  __shared__ float  pdBuf[24];
  __shared__ float  pdW[128];
  __shared__ float  tBuf[128];
  __shared__ float  sigBuf[128];
  __shared__ float  rgbBuf[128 * 3];
  __shared__ float  red3[3 * 256];
  __shared__ int    bad;

  const int b   = blockIdx.x;
  const int tid = threadIdx.x;

  // ---- positional encodings ----
  if (tid < 128) {
    const int m = tid;
    float tv = tin[b*128 + m];
    tBuf[m] = tv;
    float xs[3];
#pragma unroll
    for (int c = 0; c < 3; ++c) xs[c] = ro[b*3 + c] + tv * rd[b*3 + c];
#pragma unroll
    for (int i = 0; i < 10; ++i)
#pragma unroll
      for (int c = 0; c < 3; ++c) {
        float a = ldexpf(xs[c], i);                 // sin(2^i*pi*x) = sinpi(2^i*x)
        pxh[m*64 + i*6 + c]     = __float2half(sinpif(a));
        pxh[m*64 + i*6 + 3 + c] = __float2half(cospif(a));
      }
#pragma unroll
    for (int j = 60; j < 64; ++j) pxh[m*64 + j] = __float2half(0.f);
  } else if (tid < 152) {
    int j = tid - 128;
    int i = j / 6, r = j % 6;
    float a = ldexpf(rd[b*3 + (r % 3)], i);
    pdBuf[j] = (r < 3) ? sinpif(a) : cospif(a);
  }
  __syncthreads();
  if (tid >= 128) {                    // pdW[c] = sum_j pd[j]*Wm[256+j][c]
    int c = tid - 128;
    float s = 0.f;
#pragma unroll
    for (int j = 0; j < 24; ++j) s += pdBuf[j] * Wm[(256 + j)*128 + c];
    pdW[c] = s;
  }
  __syncthreads();

  // ---- trunk ----
  if (!useMfma ||
      !mfma_layer<8>(act, pxh, nullptr, nullptr, 0, wsHi + OFF_W0T, wsLo + OFF_W0T,
                     nullptr, W0, 256, b0, 0, nullptr, true, tid, &bad))
    dense_layer(act, pxh, nullptr, W0, 256, b0, 0, true, 256, 0.f, true, tid);
  for (int i = 0; i < 4; ++i)
    if (!useMfma ||
        !mfma_layer<8>(act, pxh, wsHi + OFF_WHT + i*65536, wsLo + OFF_WHT + i*65536, 256,
                       nullptr, nullptr, Wh + i*65536, nullptr, 256, bh + i*256, 8,
                       nullptr, true, tid, &bad))
      dense_layer(act, pxh, Wh + i*65536, nullptr, 256, bh + i*256, 4, false, 256, 0.f, true, tid);
  if (!useMfma ||
      !mfma_layer<8>(act, pxh, wsHi + OFF_W5AT, wsLo + OFF_W5AT, 256,
                     wsHi + OFF_W5BT, wsLo + OFF_W5BT, W5, W5 + 65536, 256, b5, 8,
                     nullptr, true, tid, &bad))
    dense_layer(act, pxh, W5, W5 + 65536, 256, b5, 4, true, 256, 0.f, true, tid);
  if (!useMfma ||
      !mfma_layer<8>(act, pxh, wsHi + OFF_W6T, wsLo + OFF_W6T, 256,
                     nullptr, nullptr, W6, nullptr, 256, b6, 8, nullptr, true, tid, &bad))
    dense_layer(act, pxh, W6, nullptr, 256, b6, 4, false, 256, 0.f, true, tid);
  if (!useMfma ||
      !mfma_layer<8>(act, pxh, wsHi + OFF_W7T, wsLo + OFF_W7T, 256,
                     nullptr, nullptr, W7, nullptr, 256, b7, 8, nullptr, true, tid, &bad))
    dense_layer(act, pxh, W7, nullptr, 256, b7, 4, false, 256, 0.f, true, tid);

  // sigma = relu(h @ Ws + bs)
  {
    const int m = tid >> 1, q = tid & 1;
    float s = 0.f;
    for (int k = q*128; k < q*128 + 128; ++k) s += act[m*AST + k] * Wsig[k];
    red3[tid] = s;
    __syncthreads();
    if (tid < 128) sigBuf[tid] = fmaxf(red3[2*tid] + red3[2*tid + 1] + bs[0], 0.f);
    __syncthreads();
  }

  // feat = h @ Wf + bf (no relu)
  if (!useMfma ||
      !mfma_layer<8>(act, pxh, wsHi + OFF_WFT, wsLo + OFF_WFT, 256,
                     nullptr, nullptr, Wf, nullptr, 256, bfb, 8, nullptr, false, tid, &bad))
    dense_layer(act, pxh, Wf, nullptr, 256, bfb, 4, false, 256, 0.f, false, tid);

  // h2 = relu([feat, pd] @ Wm + bm), N=128
  if (!useMfma ||
      !mfma_layer<4>(act, pxh, wsHi + OFF_WMAT, wsLo + OFF_WMAT, 256,
                     nullptr, nullptr, Wm, nullptr, 128, bm, 8, pdW, true, tid, &bad))
    dense_layer(act, pxh, Wm, nullptr, 128, bm, 4, false, 128, pdW[tid & 127], true, tid);

  // rgb = sigmoid(h2 @ Wr + br)
  {
    const int m = tid >> 1, q = tid & 1;
    float r0s = 0.f, r1s = 0.f, r2s = 0.f;
    for (int k = q*64; k < q*64 + 64; ++k) {
      float hv = act[m*AST + k];
      r0s += hv * Wr[k*3 + 0];
      r1s += hv * Wr[k*3 + 1];
      r2s += hv * Wr[k*3 + 2];
    }
    __syncthreads();
    red3[tid] = r0s; red3[256 + tid] = r1s; red3[512 + tid] = r2s;
    __syncthreads();
    if (tid < 128) {
#pragma unroll
      for (int c = 0; c < 3; ++c) {
        float sm = red3[c*256 + 2*tid] + red3[c*256 + 2*tid + 1] + br[c];
        rgbBuf[tid*3 + c] = 1.f / (1.f + expf(-sm));
      }
    }
    __syncthreads();
  }

  // volume rendering scan
  if (tid == 0) {
    float T = 1.f, c0 = 0.f, c1 = 0.f, c2 = 0.f, wsum = 0.f;
    for (int m = 0; m < 128; ++m) {
      float delta = (m < 127) ? (tBuf[m + 1] - tBuf[m]) : 1e8f;
      float e = expf(-sigBuf[m] * delta);
      float w = T * (1.f - e);
      c0 += w * rgbBuf[m*3 + 0];
      c1 += w * rgbBuf[m*3 + 1];
      c2 += w * rgbBuf[m*3 + 2];
      wsum += w;
      T *= e;
    }
    float bg = 1.f - wsum;               // C_BG = (1,1,1)
    out[b*3 + 0] = c0 + bg;
    out[b*3 + 1] = c1 + bg;
    out[b*3 + 2] = c2 + bg;
  }
}

extern "C" void kernel_launch(void* const* d_in, const int* in_sizes, int n_in,
                              void* d_out, int out_size, void* d_ws, size_t ws_size,
                              hipStream_t stream) {
  const float* ro  = (const float*)d_in[0];
  const float* rd  = (const float*)d_in[1];
  const float* t   = (const float*)d_in[2];
  const float* W0  = (const float*)d_in[3];
  const float* b0  = (const float*)d_in[4];
  const float* Wh  = (const float*)d_in[5];
  const float* bh  = (const float*)d_in[6];
  const float* W5  = (const float*)d_in[7];
  const float* b5  = (const float*)d_in[8];
  const float* W6  = (const float*)d_in[9];
  const float* b6  = (const float*)d_in[10];
  const float* W7  = (const float*)d_in[11];
  const float* b7  = (const float*)d_in[12];
  const float* Wsg = (const float*)d_in[13];
  const float* bs  = (const float*)d_in[14];
  const float* Wf  = (const float*)d_in[15];
  const float* bfb = (const float*)d_in[16];
  const float* Wm  = (const float*)d_in[17];
  const float* bm  = (const float*)d_in[18];
  const float* Wr  = (const float*)d_in[19];
  const float* br  = (const float*)d_in[20];
  float* out = (float*)d_out;

  const size_t need = (size_t)2 * TOT * sizeof(__bf16);
  const int useMfma = (ws_size >= need) ? 1 : 0;
  __bf16* wsHi = (__bf16*)d_ws;
  __bf16* wsLo = wsHi + TOT;

  if (useMfma)
    prep_weights<<<(TOT + 255)/256, 256, 0, stream>>>(W0, Wh, W5, W6, W7, Wf, Wm, wsHi);
  nerf_main<<<2048, 256, 0, stream>>>(ro, rd, t, W0, b0, Wh, bh, W5, b5, W6, b6,
                                      W7, b7, Wsg, bs, Wf, bfb, Wm, bm, Wr, br,
                                      wsHi, wsLo, useMfma, out);
}

// Round 11
// 1600.916 us; speedup vs baseline: 10.5622x; 2.3590x over previous
//
#include <hip/hip_runtime.h>
#include <hip/hip_fp16.h>
#include <math.h>

typedef __bf16 bf16x8 __attribute__((ext_vector_type(8)));
typedef float  f32x4  __attribute__((ext_vector_type(4)));

#define AH  264              // act plane stride (bf16); 132 dw % 32 == 4 -> conflict-free for quad layout
#define TOT 589824           // staged weight elems (hi); lo at +TOT

// staged ws layout (bf16, [n][k] transposed, zero-padded K tails)
#define OFF_W0T   0          // [256][64]
#define OFF_WHT   16384      // 4 x [256][256]
#define OFF_W5AT  278528     // [256][256]
#define OFF_W5BT  344064     // [256][64]
#define OFF_W6T   360448     // [256][256]
#define OFF_W7T   425984     // [256][256]
#define OFF_WFT   491520     // [256][256]
#define OFF_WMAT  557056     // [128][256]

__global__ void prep_weights(const float* __restrict__ W0, const float* __restrict__ Wh,
                             const float* __restrict__ W5, const float* __restrict__ W6,
                             const float* __restrict__ W7, const float* __restrict__ Wf,
                             const float* __restrict__ Wm, __bf16* __restrict__ ws) {
  int idx = blockIdx.x * blockDim.x + threadIdx.x;
  if (idx >= TOT) return;
  float v = 0.f;
  if (idx < OFF_WHT)        { int j = idx;            int n=j>>6, k=j&63;   v = (k<60)? W0[k*256+n] : 0.f; }
  else if (idx < OFF_W5AT)  { int j = idx - OFF_WHT;  int i=j>>16, r=j&65535, n=r>>8, k=r&255; v = Wh[i*65536+k*256+n]; }
  else if (idx < OFF_W5BT)  { int j = idx - OFF_W5AT; int n=j>>8, k=j&255;  v = W5[k*256+n]; }
  else if (idx < OFF_W6T)   { int j = idx - OFF_W5BT; int n=j>>6, k=j&63;   v = (k<60)? W5[(256+k)*256+n] : 0.f; }
  else if (idx < OFF_W7T)   { int j = idx - OFF_W6T;  int n=j>>8, k=j&255;  v = W6[k*256+n]; }
  else if (idx < OFF_WFT)   { int j = idx - OFF_W7T;  int n=j>>8, k=j&255;  v = W7[k*256+n]; }
  else if (idx < OFF_WMAT)  { int j = idx - OFF_WFT;  int n=j>>8, k=j&255;  v = Wf[k*256+n]; }
  else                      { int j = idx - OFF_WMAT; int n=j>>8, k=j&255;  v = Wm[k*128+n]; }
  __bf16 hi = (__bf16)v;
  ws[idx] = hi;
  ws[TOT + idx] = (__bf16)(v - (float)hi);
}

// ---- split-bf16 3-pass MFMA layer; act stored as hi/lo bf16 planes in LDS ----
// 512 threads = 8 waves. wave w: mBase=(w>>2)*64 (4 m-tiles),
// nBase=(w&3)*NT*16 (NT n-tiles). In-place: compute -> barrier -> write -> barrier.
template<int NT>
__device__ void mfma_layer(__bf16* aHi, __bf16* aLo, const __half* pxh,
    const __bf16* __restrict__ wHi, const __bf16* __restrict__ wLo, int kStr, int nkc,
    const __bf16* __restrict__ xHi, const __bf16* __restrict__ xLo,  // px weights [256][64] or null
    const float* __restrict__ bias, const float* __restrict__ pdW,
    bool relu, int tid) {
  const int wave = tid >> 6, lane = tid & 63;
  const int lm = lane & 15, kq = lane >> 4;
  const int mBase = (wave >> 2) * 64;
  const int nBase = (wave & 3) * (NT * 16);
  f32x4 acc[4][NT];
#pragma unroll
  for (int mt = 0; mt < 4; ++mt)
#pragma unroll
    for (int nt = 0; nt < NT; ++nt)
#pragma unroll
      for (int e = 0; e < 4; ++e) acc[mt][nt][e] = 0.f;

  for (int kc = 0; kc < nkc; ++kc) {           // act part (K = nkc*32)
    const int kb = kc*32 + kq*8;
    bf16x8 ah[4], al[4], bh[NT], bl[NT];
#pragma unroll
    for (int mt = 0; mt < 4; ++mt) {
      const int off = (mBase + mt*16 + lm)*AH + kb;
      ah[mt] = *(const bf16x8*)(aHi + off);
      al[mt] = *(const bf16x8*)(aLo + off);
    }
#pragma unroll
    for (int nt = 0; nt < NT; ++nt) {
      const int ro = (nBase + nt*16 + lm)*kStr + kb;
      bh[nt] = *(const bf16x8*)(wHi + ro);
      bl[nt] = *(const bf16x8*)(wLo + ro);
    }
#pragma unroll
    for (int mt = 0; mt < 4; ++mt)
#pragma unroll
      for (int nt = 0; nt < NT; ++nt) {
        acc[mt][nt] = __builtin_amdgcn_mfma_f32_16x16x32_bf16(ah[mt], bh[nt], acc[mt][nt], 0, 0, 0);
        acc[mt][nt] = __builtin_amdgcn_mfma_f32_16x16x32_bf16(ah[mt], bl[nt], acc[mt][nt], 0, 0, 0);
        acc[mt][nt] = __builtin_amdgcn_mfma_f32_16x16x32_bf16(al[mt], bh[nt], acc[mt][nt], 0, 0, 0);
      }
  }
  if (xHi) {                                   // px part, K=64 (zero-padded tail)
#pragma unroll
    for (int kc = 0; kc < 2; ++kc) {
      const int kb = kc*32 + kq*8;
      bf16x8 ah[4], al[4], bh[NT], bl[NT];
#pragma unroll
      for (int mt = 0; mt < 4; ++mt) {
        const __half* pr = pxh + (mBase + mt*16 + lm)*64 + kb;
#pragma unroll
        for (int j = 0; j < 8; ++j) {
          float v = __half2float(pr[j]);
          __bf16 h = (__bf16)v;
          ah[mt][j] = h;
          al[mt][j] = (__bf16)(v - (float)h);
        }
      }
#pragma unroll
      for (int nt = 0; nt < NT; ++nt) {
        const int ro = (nBase + nt*16 + lm)*64 + kb;
        bh[nt] = *(const bf16x8*)(xHi + ro);
        bl[nt] = *(const bf16x8*)(xLo + ro);
      }
#pragma unroll
      for (int mt = 0; mt < 4; ++mt)
#pragma unroll
        for (int nt = 0; nt < NT; ++nt) {
          acc[mt][nt] = __builtin_amdgcn_mfma_f32_16x16x32_bf16(ah[mt], bh[nt], acc[mt][nt], 0, 0, 0);
          acc[mt][nt] = __builtin_amdgcn_mfma_f32_16x16x32_bf16(ah[mt], bl[nt], acc[mt][nt], 0, 0, 0);
          acc[mt][nt] = __builtin_amdgcn_mfma_f32_16x16x32_bf16(al[mt], bh[nt], acc[mt][nt], 0, 0, 0);
        }
    }
  }
  __syncthreads();                 // all reads of act complete
  // epilogue: C/D mapping row=kq*4+r, col=lm (verified r5 vs r9 bit-match)
#pragma unroll
  for (int mt = 0; mt < 4; ++mt)
#pragma unroll
    for (int nt = 0; nt < NT; ++nt) {
      const int col = nBase + nt*16 + lm;
      float bv = bias[col] + (pdW ? pdW[col] : 0.f);
#pragma unroll
      for (int r = 0; r < 4; ++r) {
        const int row = mBase + mt*16 + kq*4 + r;
        float v = acc[mt][nt][r] + bv;
        if (relu) v = fmaxf(v, 0.f);
        __bf16 h = (__bf16)v;
        aHi[row*AH + col] = h;
        aLo[row*AH + col] = (__bf16)(v - (float)h);
      }
    }
  __syncthreads();
}

__global__ __launch_bounds__(512, 2) void nerf_main(
    const float* __restrict__ ro, const float* __restrict__ rd, const float* __restrict__ tin,
    const float* __restrict__ b0, const float* __restrict__ bh,
    const float* __restrict__ b5, const float* __restrict__ b6,
    const float* __restrict__ b7,
    const float* __restrict__ Wsig, const float* __restrict__ bs,
    const float* __restrict__ bfb,
    const float* __restrict__ Wm, const float* __restrict__ bm,
    const float* __restrict__ Wr, const float* __restrict__ br,
    const __bf16* __restrict__ wsHi, const __bf16* __restrict__ wsLo,
    float* __restrict__ out) {
  __shared__ __align__(16) __bf16 aHi[128 * AH];       // 67584 B
  __shared__ __align__(16) __bf16 aLo[128 * AH];       // 67584 B
  // pxh (dead after layer 5) unioned with red (first used in sigma head)
  __shared__ __align__(16) unsigned char pxred[16384];
  __shared__ __align__(16) float  pdBuf[24];
  __shared__ __align__(16) float  pdW[128];
  __shared__ __align__(16) float  tBuf[128];
  __shared__ __align__(16) float  sigBuf[128];
  __shared__ __align__(16) float  rgbBuf[128 * 3];
  // total: 67584*2 + 16384 + 96 + 512 + 512 + 512 + 1536 = 154,720 B  (r9 proved 156,160 OK)

  __half* pxh = (__half*)pxred;        // 128*64 halves = 16384 B
  float*  red = (float*)pxred;         // 1536 floats = 6144 B (after pxh dead)

  const int b   = blockIdx.x;
  const int tid = threadIdx.x;

  // ---- positional encodings ----
  if (tid < 128) {
    const int m = tid;
    float tv = tin[b*128 + m];
    tBuf[m] = tv;
    float xs[3];
#pragma unroll
    for (int c = 0; c < 3; ++c) xs[c] = ro[b*3 + c] + tv * rd[b*3 + c];
#pragma unroll
    for (int i = 0; i < 10; ++i)
#pragma unroll
      for (int c = 0; c < 3; ++c) {
        float a = ldexpf(xs[c], i);                 // sin(2^i*pi*x) = sinpi(2^i*x)
        pxh[m*64 + i*6 + c]     = __float2half(sinpif(a));
        pxh[m*64 + i*6 + 3 + c] = __float2half(cospif(a));
      }
#pragma unroll
    for (int j = 60; j < 64; ++j) pxh[m*64 + j] = __float2half(0.f);
  } else if (tid < 152) {
    int j = tid - 128;
    int i = j / 6, r = j % 6;
    float a = ldexpf(rd[b*3 + (r % 3)], i);
    pdBuf[j] = (r < 3) ? sinpif(a) : cospif(a);
  }
  __syncthreads();
  if (tid >= 128 && tid < 256) {       // pdW[c] = sum_j pd[j]*Wm[256+j][c]
    int c = tid - 128;
    float s = 0.f;
#pragma unroll
    for (int j = 0; j < 24; ++j) s += pdBuf[j] * Wm[(256 + j)*128 + c];
    pdW[c] = s;
  }
  __syncthreads();

  // ---- trunk ----
  mfma_layer<4>(aHi, aLo, pxh, nullptr, nullptr, 0, 0,
                wsHi + OFF_W0T, wsLo + OFF_W0T, b0, nullptr, true, tid);
  for (int i = 0; i < 4; ++i)
    mfma_layer<4>(aHi, aLo, pxh, wsHi + OFF_WHT + i*65536, wsLo + OFF_WHT + i*65536, 256, 8,
                  nullptr, nullptr, bh + i*256, nullptr, true, tid);
  mfma_layer<4>(aHi, aLo, pxh, wsHi + OFF_W5AT, wsLo + OFF_W5AT, 256, 8,
                wsHi + OFF_W5BT, wsLo + OFF_W5BT, b5, nullptr, true, tid);
  mfma_layer<4>(aHi, aLo, pxh, wsHi + OFF_W6T, wsLo + OFF_W6T, 256, 8,
                nullptr, nullptr, b6, nullptr, true, tid);
  mfma_layer<4>(aHi, aLo, pxh, wsHi + OFF_W7T, wsLo + OFF_W7T, 256, 8,
                nullptr, nullptr, b7, nullptr, true, tid);

  // sigma = relu(h @ Ws + bs): 4 threads per sample over K=256   (pxh now dead)
  {
    const int m = tid >> 2, q = tid & 3;
    float s = 0.f;
    for (int k = q*64; k < q*64 + 64; ++k)
      s += ((float)aHi[m*AH + k] + (float)aLo[m*AH + k]) * Wsig[k];
    red[tid] = s;
    __syncthreads();
    if (tid < 128)
      sigBuf[tid] = fmaxf(red[4*tid] + red[4*tid+1] + red[4*tid+2] + red[4*tid+3] + bs[0], 0.f);
    __syncthreads();
  }

  // feat = h @ Wf + bf (no relu)
  mfma_layer<4>(aHi, aLo, nullptr, wsHi + OFF_WFT, wsLo + OFF_WFT, 256, 8,
                nullptr, nullptr, bfb, nullptr, false, tid);

  // h2 = relu([feat, pd] @ Wm + bm), N=128 (pd folded via pdW)
  mfma_layer<2>(aHi, aLo, nullptr, wsHi + OFF_WMAT, wsLo + OFF_WMAT, 256, 8,
                nullptr, nullptr, bm, pdW, true, tid);

  // rgb = sigmoid(h2 @ Wr + br): 4 threads per sample over K=128
  {
    const int m = tid >> 2, q = tid & 3;
    float r0s = 0.f, r1s = 0.f, r2s = 0.f;
    for (int k = q*32; k < q*32 + 32; ++k) {
      float hv = (float)aHi[m*AH + k] + (float)aLo[m*AH + k];
      r0s += hv * Wr[k*3 + 0];
      r1s += hv * Wr[k*3 + 1];
      r2s += hv * Wr[k*3 + 2];
    }
    red[tid] = r0s; red[512 + tid] = r1s; red[1024 + tid] = r2s;
    __syncthreads();
    if (tid < 128) {
#pragma unroll
      for (int c = 0; c < 3; ++c) {
        float sm = red[c*512 + 4*tid] + red[c*512 + 4*tid+1]
                 + red[c*512 + 4*tid+2] + red[c*512 + 4*tid+3] + br[c];
        rgbBuf[tid*3 + c] = 1.f / (1.f + expf(-sm));
      }
    }
    __syncthreads();
  }

  // volume rendering: serial exclusive-transmittance scan
  if (tid == 0) {
    float T = 1.f, c0 = 0.f, c1 = 0.f, c2 = 0.f, wsum = 0.f;
    for (int m = 0; m < 128; ++m) {
      float delta = (m < 127) ? (tBuf[m + 1] - tBuf[m]) : 1e8f;
      float e = expf(-sigBuf[m] * delta);
      float w = T * (1.f - e);
      c0 += w * rgbBuf[m*3 + 0];
      c1 += w * rgbBuf[m*3 + 1];
      c2 += w * rgbBuf[m*3 + 2];
      wsum += w;
      T *= e;
    }
    float bg = 1.f - wsum;               // C_BG = (1,1,1)
    out[b*3 + 0] = c0 + bg;
    out[b*3 + 1] = c1 + bg;
    out[b*3 + 2] = c2 + bg;
  }
}

extern "C" void kernel_launch(void* const* d_in, const int* in_sizes, int n_in,
                              void* d_out, int out_size, void* d_ws, size_t ws_size,
                              hipStream_t stream) {
  const float* ro  = (const float*)d_in[0];
  const float* rd  = (const float*)d_in[1];
  const float* t   = (const float*)d_in[2];
  const float* W0  = (const float*)d_in[3];
  const float* b0  = (const float*)d_in[4];
  const float* Wh  = (const float*)d_in[5];
  const float* bh  = (const float*)d_in[6];
  const float* W5  = (const float*)d_in[7];
  const float* b5  = (const float*)d_in[8];
  const float* W6  = (const float*)d_in[9];
  const float* b6  = (const float*)d_in[10];
  const float* W7  = (const float*)d_in[11];
  const float* b7  = (const float*)d_in[12];
  const float* Wsg = (const float*)d_in[13];
  const float* bs  = (const float*)d_in[14];
  const float* Wf  = (const float*)d_in[15];
  const float* bfb = (const float*)d_in[16];
  const float* Wm  = (const float*)d_in[17];
  const float* bm  = (const float*)d_in[18];
  const float* Wr  = (const float*)d_in[19];
  const float* br  = (const float*)d_in[20];
  float* out = (float*)d_out;

  __bf16* wsHi = (__bf16*)d_ws;        // 2*TOT bf16 = 2.36 MB (proven sufficient r9)
  __bf16* wsLo = wsHi + TOT;

  prep_weights<<<(TOT + 255)/256, 256, 0, stream>>>(W0, Wh, W5, W6, W7, Wf, Wm, wsHi);
  nerf_main<<<2048, 512, 0, stream>>>(ro, rd, t, b0, bh, b5, b6, b7,
                                      Wsg, bs, bfb, Wm, bm, Wr, br,
                                      wsHi, wsLo, out);
}